// Round 8
// baseline (102.627 us; speedup 1.0000x reference)
//
#include <hip/hip_runtime.h>
#include <hip/hip_bf16.h>
#include <stdint.h>

// Problem constants (fixed by the reference)
#define NQ    32768
#define NKV   32768
#define CDIM  256
#define NHEADS 8
#define NPTS  4
// Ch = 32, pairs (h,p) = 32, loc cols used = even cols only (x coord)

using bf16x8 = __attribute__((ext_vector_type(8))) short;
using f32x4  = __attribute__((ext_vector_type(4))) float;
using u16x8  = __attribute__((ext_vector_type(8))) ushort;

static __device__ __forceinline__ ushort f2bf(float f) {
  uint32_t u = __float_as_uint(f);
  return (ushort)((u + 0x7FFFu + ((u >> 16) & 1u)) >> 16);  // RNE
}
static __device__ __forceinline__ float bf2f(ushort h) {
  return __uint_as_float(((uint32_t)h) << 16);
}
static __device__ __forceinline__ void async16(const void* g, void* l) {
  __builtin_amdgcn_global_load_lds(
      (const __attribute__((address_space(1))) uint32_t*)g,
      (__attribute__((address_space(3))) uint32_t*)l, 16, 0, 0);
}
#define WAIT_VM(N) do { asm volatile("s_waitcnt vmcnt(" #N ")" ::: "memory"); \
                        __builtin_amdgcn_sched_barrier(0); } while (0)

// K0b: W [256][256] f32 -> W^T [256][256] bf16 (row j holds column j of W,
// k-contiguous — the layout the MFMA B-operand wants).
__global__ __launch_bounds__(256) void transpose_w(const float* __restrict__ W,
                                                   ushort* __restrict__ WT) {
  int j = blockIdx.x, k = threadIdx.x;
  WT[j * 256 + k] = f2bf(W[k * 256 + j]);
}

// ---------------------------------------------------------------------------
// K3: bf16 MFMA GEMM  C[M,256] = A[M,256] * B + bias   (A already bf16)
__global__ __launch_bounds__(256) void gemm_mfma(
    const ushort* __restrict__ A, const ushort* __restrict__ BT,
    const float* __restrict__ bias, ushort* __restrict__ Cb,
    float* __restrict__ Cf, int out_bf16) {
  __shared__ ushort Alds[128 * 32];
  __shared__ ushort Blds[128 * 32];
  const int t = threadIdx.x;
  const int wave = t >> 6, lane = t & 63;
  const int mt = blockIdx.x >> 1, nt = blockIdx.x & 1;
  const int m0 = mt * 128, n0 = nt * 128;
  const int wr = wave >> 1, wc = wave & 1;
  const int r16 = lane & 15, kb = (lane >> 4) * 8;

  f32x4 acc[4][4] = {};

  for (int kt = 0; kt < 256; kt += 32) {
    __syncthreads();
#pragma unroll
    for (int it = 0; it < 2; ++it) {
      int c = it * 256 + t;
      int row = c >> 2, cc = c & 3;
      async16(A  + ((size_t)(m0 + row) * 256 + kt + cc * 8),
              Alds + (size_t)(it * 256 + wave * 64) * 8);
      async16(BT + ((size_t)(n0 + row) * 256 + kt + cc * 8),
              Blds + (size_t)(it * 256 + wave * 64) * 8);
    }
    __syncthreads();

    bf16x8 af[4], bfr[4];
#pragma unroll
    for (int m = 0; m < 4; ++m)
      af[m] = *(const bf16x8*)&Alds[(wr * 64 + m * 16 + r16) * 32 + kb];
#pragma unroll
    for (int n = 0; n < 4; ++n)
      bfr[n] = *(const bf16x8*)&Blds[(wc * 64 + n * 16 + r16) * 32 + kb];
#pragma unroll
    for (int m = 0; m < 4; ++m)
#pragma unroll
      for (int n = 0; n < 4; ++n)
        acc[m][n] = __builtin_amdgcn_mfma_f32_16x16x32_bf16(af[m], bfr[n],
                                                            acc[m][n], 0, 0, 0);
  }

  const int rg = lane >> 4;
#pragma unroll
  for (int m = 0; m < 4; ++m)
#pragma unroll
    for (int n = 0; n < 4; ++n) {
      int gc = n0 + wc * 64 + n * 16 + r16;
      float bb = bias[gc];
#pragma unroll
      for (int r = 0; r < 4; ++r) {
        int gr = m0 + wr * 64 + m * 16 + rg * 4 + r;
        float v = acc[m][n][r] + bb;
        if (out_bf16) Cb[(size_t)gr * 256 + gc] = f2bf(v);
        else          Cf[(size_t)gr * 256 + gc] = v;
      }
    }
}

// K1: value GEMM. A is f32 (converted to bf16 in-register during staging —
// fuses the old convert_val pass) and C is written TRANSPOSED to
// vtabT[H][M][Ch] so sample_attn's (x0,x0+1) value pair is one contiguous
// 128B region (avg 1.5 cache lines instead of 2).
__global__ __launch_bounds__(256) void gemm_mfma_fa(
    const float* __restrict__ Af, const ushort* __restrict__ BT,
    const float* __restrict__ bias, ushort* __restrict__ CbT) {
  __shared__ ushort Alds[128 * 32];
  __shared__ ushort Blds[128 * 32];
  const int t = threadIdx.x;
  const int wave = t >> 6, lane = t & 63;
  const int mt = blockIdx.x >> 1, nt = blockIdx.x & 1;
  const int m0 = mt * 128, n0 = nt * 128;
  const int wr = wave >> 1, wc = wave & 1;
  const int r16 = lane & 15, kb = (lane >> 4) * 8;

  f32x4 acc[4][4] = {};

  for (int kt = 0; kt < 256; kt += 32) {
    __syncthreads();
#pragma unroll
    for (int it = 0; it < 2; ++it) {  // B via global_load_lds (bf16 already)
      int c = it * 256 + t;
      int row = c >> 2, cc = c & 3;
      async16(BT + ((size_t)(n0 + row) * 256 + kt + cc * 8),
              Blds + (size_t)(it * 256 + wave * 64) * 8);
    }
#pragma unroll
    for (int it = 0; it < 2; ++it) {  // A: f32 -> reg -> bf16 -> ds_write
      int c = it * 256 + t;
      int row = c >> 2, cc = c & 3;
      const float* src = Af + (size_t)(m0 + row) * 256 + kt + cc * 8;
      f32x4 a = *(const f32x4*)src;
      f32x4 b = *(const f32x4*)(src + 4);
      u16x8 w;
#pragma unroll
      for (int e = 0; e < 4; ++e) { w[e] = f2bf(a[e]); w[4 + e] = f2bf(b[e]); }
      *(u16x8*)&Alds[(size_t)c * 8] = w;   // c*8 == row*32 + cc*8
    }
    __syncthreads();  // covers vmcnt (B) + lgkm (A ds_write)

    bf16x8 af[4], bfr[4];
#pragma unroll
    for (int m = 0; m < 4; ++m)
      af[m] = *(const bf16x8*)&Alds[(wr * 64 + m * 16 + r16) * 32 + kb];
#pragma unroll
    for (int n = 0; n < 4; ++n)
      bfr[n] = *(const bf16x8*)&Blds[(wc * 64 + n * 16 + r16) * 32 + kb];
#pragma unroll
    for (int m = 0; m < 4; ++m)
#pragma unroll
      for (int n = 0; n < 4; ++n)
        acc[m][n] = __builtin_amdgcn_mfma_f32_16x16x32_bf16(af[m], bfr[n],
                                                            acc[m][n], 0, 0, 0);
  }

  const int rg = lane >> 4;
#pragma unroll
  for (int m = 0; m < 4; ++m)
#pragma unroll
    for (int n = 0; n < 4; ++n) {
      int gc = n0 + wc * 64 + n * 16 + r16;   // h = gc>>5, ch = gc&31
      float bb = bias[gc];
#pragma unroll
      for (int r = 0; r < 4; ++r) {
        int gr = m0 + wr * 64 + m * 16 + rg * 4 + r;
        CbT[((size_t)(gc >> 5) * NKV + gr) * 32 + (gc & 31)] =
            f2bf(acc[m][n][r] + bb);
      }
    }
}

// ---------------------------------------------------------------------------
// K2a: loc_raw[N,64] = query @ [Wr_even | Wo_even]   (fp32 score path).
__global__ __launch_bounds__(256) void loc_gemm(const float* __restrict__ Q,
                                                const float* __restrict__ Wr,
                                                const float* __restrict__ Wo,
                                                float* __restrict__ locr) {
  __shared__ float AT[64][68];
  __shared__ float Bl[64][64];
  const int m0 = blockIdx.x * 64;
  const int t = threadIdx.x;
  const int tr = t >> 4, tc = t & 15;
  float acc[4][4] = {};

  for (int k0 = 0; k0 < 256; k0 += 64) {
    __syncthreads();
#pragma unroll
    for (int i = 0; i < 4; ++i) {
      int row = (t >> 4) + 16 * i;
      int kk = (t & 15) * 4;
      float4 v = *(const float4*)&Q[(size_t)(m0 + row) * 256 + k0 + kk];
      AT[kk + 0][row] = v.x; AT[kk + 1][row] = v.y;
      AT[kk + 2][row] = v.z; AT[kk + 3][row] = v.w;
    }
#pragma unroll
    for (int i = 0; i < 16; ++i) {
      int j = t & 63;
      int kk = (t >> 6) + 4 * i;
      float v = (j < 32) ? Wr[(size_t)(k0 + kk) * 64 + 2 * j]
                         : Wo[(size_t)(k0 + kk) * 64 + 2 * (j - 32)];
      Bl[kk][j] = v;
    }
    __syncthreads();
#pragma unroll 8
    for (int kk = 0; kk < 64; ++kk) {
      float4 a = *(const float4*)&AT[kk][tr * 4];
      float4 b = *(const float4*)&Bl[kk][tc * 4];
      float av[4] = {a.x, a.y, a.z, a.w};
      float bv4[4] = {b.x, b.y, b.z, b.w};
#pragma unroll
      for (int i = 0; i < 4; ++i)
#pragma unroll
        for (int jj = 0; jj < 4; ++jj) acc[i][jj] += av[i] * bv4[jj];
    }
  }
#pragma unroll
  for (int i = 0; i < 4; ++i)
#pragma unroll
    for (int jj = 0; jj < 4; ++jj)
      locr[(size_t)(m0 + tr * 4 + i) * 64 + tc * 4 + jj] = acc[i][jj];
}

// ---------------------------------------------------------------------------
// K2b: fused sampling + attention — hybrid staging for occupancy.
// Wave = 1 query row. v pairs staged to LDS (4KB/wave, from vtabT, issued
// FIRST so their latency hides under the whole score phase). k is per-lane
// register loads: lane l<32 reads its own point's x0 row, lane l>=32 the x1
// row — x0/x1 are lane-local so ZERO broadcast shuffles, no k-LDS, no
// k-ds_reads (r5<->r6 showed divergent k loads cost ~= staged). LDS/block
// drops 48KB->16KB and launch_bounds(256,4) caps VGPR at 128 -> 16 waves/CU
// (2x round 7) to lift VALUBusy out of the 42% latency hole.
//  v pair pt (128B = rows x0,x0+1 of head pt>>2): pos p holds chunk p^(pt&7)
__global__ __launch_bounds__(256, 4) void sample_attn(
    const float* __restrict__ query, const float* __restrict__ key,
    const ushort* __restrict__ vtabT, const float* __restrict__ locr,
    const float* __restrict__ br, const float* __restrict__ bo,
    ushort* __restrict__ out2) {
  __shared__ char smem[4][4096];            // v pairs only: 4KB per wave
  const int wave = threadIdx.x >> 6, l = threadIdx.x & 63;
  const int j = l & 31;                     // point id (dup in both halves)
  const int n = blockIdx.x * 4 + wave;
  const int Mm1 = NKV - 1;
  char* vbuf = smem[wave];

  // sampling location for point j (identical in both lane halves)
  float rr = locr[(size_t)n * 64 + j];
  float oo = locr[(size_t)n * 64 + 32 + j];
  float ref = 1.0f / (1.0f + expf(-(rr + br[2 * j])));
  float x = (ref + (oo + bo[2 * j])) * (float)Mm1;
  float xf = floorf(x);
  int x0 = (int)fminf(fmaxf(xf, 0.0f), (float)Mm1);
  int x1 = (x0 + 1 > Mm1) ? Mm1 : x0 + 1;
  float wx = x - (float)x0;
  float w0 = 1.0f - wx;

  // ---- stage v pairs FIRST (longest latency window): 4 instrs
  {
    const int pg3 = l >> 3, c7 = l & 7;
    const int sc = c7 ^ pg3;               // pg&7 == pg3
#pragma unroll
    for (int i = 0; i < 4; ++i) {
      int pg = i * 8 + pg3;
      int row = __shfl(x0, pg, 64);
      async16(vtabT + ((size_t)(pg >> 2) * NKV + row) * 32 + sc * 8,
              vbuf + i * 1024);
    }
  }
  __builtin_amdgcn_sched_barrier(0);

  // ---- k + q per-lane register loads (lane-local rows, no shuffles)
  const int myrow = (l < 32) ? x0 : x1;
  const float* kr = key + (size_t)myrow * 256 + (j >> 2) * 32;
  const float* qr = query + (size_t)n * 256 + (j >> 2) * 32;
  f32x4 kv[8], qv[8];
#pragma unroll
  for (int c = 0; c < 8; ++c) kv[c] = *(const f32x4*)(kr + c * 4);
#pragma unroll
  for (int c = 0; c < 8; ++c) qv[c] = *(const f32x4*)(qr + c * 4);
  __builtin_amdgcn_sched_barrier(0);

  // ---- score: lane (which=l>>5, pt=j) holds q . k_which[pt]
  float dot = 0.f;
#pragma unroll
  for (int c = 0; c < 8; ++c)
#pragma unroll
    for (int e = 0; e < 4; ++e) dot += qv[c][e] * kv[c][e];

  float other = __shfl_xor(dot, 32, 64);
  float d0 = (l < 32) ? dot : other;
  float d1 = (l < 32) ? other : dot;
  float score = (w0 * d0 + wx * d1) * 0.17677669529663687f;  // 1/sqrt(32)

  // softmax over the head's 4 points (quad lanes; same in both halves)
  float m1 = fmaxf(score, __shfl_xor(score, 1, 64));
  float mx = fmaxf(m1, __shfl_xor(m1, 2, 64));
  float e0 = expf(score - mx);
  float s1 = e0 + __shfl_xor(e0, 1, 64);
  float ssum = s1 + __shfl_xor(s1, 2, 64);
  float attn = e0 / ssum;
  // v-pair block holds rows [x0, x0+1]; when x0==M-1 its 2nd half is garbage
  // but the reference value is v[x0] exactly (g0==g1): fold w0+wx=1 into c0.
  int edge = (x0 == Mm1);
  float c1v = edge ? 0.0f : attn * wx;
  float c0v = edge ? attn * (w0 + wx) : attn * w0;

  // ---- output: lane (oh=l>>3, os=l&7) owns channels [os*4, os*4+4) of oh
  const int oh = l >> 3, os = l & 7;
  float cc0[4], cc1[4];
#pragma unroll
  for (int m = 0; m < 4; ++m) {
    cc0[m] = __shfl(c0v, oh * 4 + m, 64);
    cc1[m] = __shfl(c1v, oh * 4 + m, 64);
  }

  WAIT_VM(0);  // v landed (k/q already drained via register deps)

  float acc[4] = {};
#pragma unroll
  for (int m = 0; m < 4; ++m) {
    int pt = oh * 4 + m;
    int pos0 = (os >> 1) ^ (pt & 7);        // row x0, chunk os>>1
    int pos1 = (4 + (os >> 1)) ^ (pt & 7);  // row x0+1
    const char* pb = vbuf + pt * 128 + (os & 1) * 8;
    ushort4 v0 = *(const ushort4*)(pb + pos0 * 16);
    ushort4 v1 = *(const ushort4*)(pb + pos1 * 16);
#pragma unroll
    for (int e = 0; e < 4; ++e)
      acc[e] += cc0[m] * bf2f((&v0.x)[e]) + cc1[m] * bf2f((&v1.x)[e]);
  }
  ushort4 ow;
#pragma unroll
  for (int e = 0; e < 4; ++e) (&ow.x)[e] = f2bf(acc[e]);
  *(ushort4*)(out2 + (size_t)n * 256 + oh * 32 + os * 4) = ow;
}

// ---------------------------------------------------------------------------
extern "C" void kernel_launch(void* const* d_in, const int* in_sizes, int n_in,
                              void* d_out, int out_size, void* d_ws, size_t ws_size,
                              hipStream_t stream) {
  const float* query = (const float*)d_in[0];
  const float* key   = (const float*)d_in[1];
  const float* value = (const float*)d_in[2];
  const float* Wr    = (const float*)d_in[3];
  const float* br    = (const float*)d_in[4];
  const float* Wo    = (const float*)d_in[5];
  const float* bo    = (const float*)d_in[6];
  const float* Wv    = (const float*)d_in[7];
  const float* bv    = (const float*)d_in[8];
  const float* Wout  = (const float*)d_in[9];
  const float* bout  = (const float*)d_in[10];
  float* out = (float*)d_out;

  char* ws = (char*)d_ws;
  ushort* out2  = (ushort*)(ws);                         // 16 MB
  ushort* vtabT = (ushort*)(ws + (16u << 20));           // 16 MB [H][M][Ch]
  float*  locr  = (float*) (ws + (32u << 20));           //  8 MB
  ushort* WvT   = (ushort*)(ws + (40u << 20));           // 128 KB
  ushort* WoT   = (ushort*)(ws + (40u << 20) + (1u << 17));

  transpose_w<<<256, 256, 0, stream>>>(Wv, WvT);
  transpose_w<<<256, 256, 0, stream>>>(Wout, WoT);
  // vtabT[h][m][ch] = bf16(value @ Wv + bv)  (A f32->bf16 during staging)
  gemm_mfma_fa<<<(NQ / 128) * 2, 256, 0, stream>>>(value, WvT, bv, vtabT);
  // loc_raw = query @ [Wr_even | Wo_even]  (fp32)
  loc_gemm<<<NQ / 64, 256, 0, stream>>>(query, Wr, Wo, locr);
  // fused sampling/attention -> out2 (bf16)
  sample_attn<<<NQ / 4, 256, 0, stream>>>(query, key, vtabT, locr, br, bo, out2);
  // out = out2 @ Wout + bout  (f32)
  gemm_mfma<<<(NQ / 128) * 2, 256, 0, stream>>>(out2, WoT, bout, nullptr, out, 0);
}